// Round 11
// baseline (164.779 us; speedup 1.0000x reference)
//
#include <hip/hip_runtime.h>

// MQA fused layer, MI355X gfx950.
// B=4 T=4096 C=1024 H=16 D=64 W=128 NB=32.
// Pipeline: prep (cvt x, transpose-cvt weights, trig table — one dispatch) |
//           KV-GEMM 128^2 (fused RMS+RoPE K / V-transpose epilogue) |
//           Q-GEMM 256^2 8-phase ALL-ASM-SYNC (fused RMS+RoPE epilogue) |
//           blocked sliding-window attention | proj GEMM 256^2 -> d_out.

typedef __attribute__((ext_vector_type(8))) short short8;
typedef __attribute__((ext_vector_type(4))) float f32x4;
typedef __attribute__((ext_vector_type(16))) float f32x16;
typedef __attribute__((ext_vector_type(4))) unsigned uint4v;

#define DEV static __device__ __forceinline__

DEV unsigned short f2bf(float f) {           // fp32 -> bf16 RNE
  unsigned u = __builtin_bit_cast(unsigned, f);
  u += 0x7fffu + ((u >> 16) & 1u);
  return (unsigned short)(u >> 16);
}
DEV float bf2f(unsigned short s) {
  unsigned u = ((unsigned)s) << 16;
  return __builtin_bit_cast(float, u);
}
DEV unsigned cvtpk(float a, float b) {       // {bf16(a), bf16(b)} packed
  unsigned r;
  asm("v_cvt_pk_bf16_f32 %0, %1, %2" : "=v"(r) : "v"(a), "v"(b));
  return r;
}

DEV f32x4 mfma16(short8 a, short8 b, f32x4 c) {
  return __builtin_amdgcn_mfma_f32_16x16x32_bf16(a, b, c, 0, 0, 0);
}
DEV f32x16 mfma32(short8 a, short8 b, f32x16 c) {
  return __builtin_amdgcn_mfma_f32_32x32x16_bf16(a, b, c, 0, 0, 0);
}

// async global->LDS, 16B per lane
DEV void gload16(const void* g, void* l) {
  __builtin_amdgcn_global_load_lds(
      (const __attribute__((address_space(1))) unsigned int*)(unsigned long long)g,
      (__attribute__((address_space(3))) unsigned int*)(unsigned int)(unsigned long long)l,
      16, 0, 0);
}

// inline-asm ds_read_b128 on a raw 32-bit LDS byte address (invisible to alias
// analysis; hazards covered manually by the asm barrier/wait ledger below).
DEV short8 dsr128(unsigned a) {
  short8 r;
  asm volatile("ds_read_b128 %0, %1" : "=v"(r) : "v"(a));
  return r;
}

// ALL-ASM sync: the compiler cannot attach an implicit vmcnt(0) drain to an
// inline-asm s_barrier (it does to builtin barriers when global_load_lds DMAs
// are outstanding — suspected cause of the counted-vmcnt pipeline never
// engaging in R4-R10). "memory" clobber still orders all real memory ops.
#define ASMBAR do { asm volatile("s_barrier" ::: "memory"); } while (0)
#define LGKM0  asm volatile("s_waitcnt lgkmcnt(0)" ::: "memory")
#define VMCNT2 asm volatile("s_waitcnt vmcnt(2)" ::: "memory")
#define VMCNT4 asm volatile("s_waitcnt vmcnt(4)" ::: "memory")
#define SCHED0 __builtin_amdgcn_sched_barrier(0)   // rule #18 fence after LGKM0

// ---------------- kernel: merged prep (cvt x | tcvt w_attn | tcvt w_proj |
//                  trig table) — one dispatch, branch by block range ----------
__global__ __launch_bounds__(256) void k_prep(const float* __restrict__ x,
                                              short* __restrict__ xb,
                                              const float* __restrict__ wa,
                                              short* __restrict__ wabt,
                                              const float* __restrict__ wp,
                                              short* __restrict__ wpbt,
                                              const int* __restrict__ pos,
                                              float* __restrict__ trig) {
  __shared__ float tl[32][33];
  int bid = blockIdx.x, tid = threadIdx.x;
  if (bid < 16384) {                                 // cvt x -> bf16
    int i = bid * 256 + tid;
    float4 v = ((const float4*)x)[i];
    short4 o;
    o.x = (short)f2bf(v.x); o.y = (short)f2bf(v.y);
    o.z = (short)f2bf(v.z); o.w = (short)f2bf(v.w);
    ((short4*)xb)[i] = o;
    return;
  }
  if (bid < 16384 + 1152 + 1024) {                   // transpose-cvt weights
    const float* W; short* Wt; int N, local;
    if (bid < 16384 + 1152) { local = bid - 16384; W = wa; Wt = wabt; N = 1152; }
    else { local = bid - 16384 - 1152; W = wp; Wt = wpbt; N = 1024; }
    int k0 = (local & 31) * 32, n0 = (local >> 5) * 32;
    int tx = tid & 31, ty = tid >> 5;
#pragma unroll
    for (int i = 0; i < 4; ++i)
      tl[ty + i * 8][tx] = W[(size_t)(k0 + ty + i * 8) * N + n0 + tx];
    __syncthreads();
#pragma unroll
    for (int i = 0; i < 4; ++i)
      Wt[(size_t)(n0 + ty + i * 8) * 1024 + k0 + tx] = (short)f2bf(tl[tx][ty + i * 8]);
    return;
  }
  {                                                  // trig table [4096][32]
    int idx = (bid - 16384 - 1152 - 1024) * 256 + tid;
    int t = idx >> 5, j = idx & 31;
    float invf = __expf((float)j * (-13.815510558f / 32.f));
    float p = (float)pos[t * 3 + (j % 3)];
    float s, c;
    sincosf(p * invf, &s, &c);
    ((float2*)trig)[idx] = make_float2(c, s);
  }
}

// ---------------- kernel: KV GEMM 128x128 (m97 structure) + fused epilogue --
__global__ __launch_bounds__(256) void k_gemmkv(const short* __restrict__ A,
                                                const short* __restrict__ Bt,
                                                const float* __restrict__ trig,
                                                const float* __restrict__ kw,
                                                short* __restrict__ kb2,
                                                short* __restrict__ vtg) {
  __shared__ short As[128 * 32];
  __shared__ short Bs[128 * 32];
  const int K = 1024;
  int bid = blockIdx.x;
  int bm = (bid & 7) * 16 + (bid >> 3);            // XCD swizzle, nwg=128
  int tid = threadIdx.x, lane = tid & 63, wid = tid >> 6;
  int wr = wid >> 1, wc = wid & 1;
  int lo = lane & 15, hi = lane >> 4;
  const short* Ab = A + (size_t)(bm * 128 + (tid >> 2)) * K + (tid & 3) * 8;
  const short* Bb = Bt + (size_t)(tid >> 2) * K + (tid & 3) * 8;
  f32x4 acc[4][4] = {};
  for (int kt = 0; kt < K; kt += 32) {
    gload16(Ab + kt,            As + tid * 8);
    gload16(Ab + kt + 64 * K,   As + 2048 + tid * 8);
    gload16(Bb + kt,            Bs + tid * 8);
    gload16(Bb + kt + 64 * K,   Bs + 2048 + tid * 8);
    __syncthreads();
    short8 a[4], b[4];
#pragma unroll
    for (int m = 0; m < 4; ++m)
      a[m] = *(const short8*)&As[(wr * 64 + m * 16 + lo) * 32 + hi * 8];
#pragma unroll
    for (int n = 0; n < 4; ++n)
      b[n] = *(const short8*)&Bs[(wc * 64 + n * 16 + lo) * 32 + hi * 8];
#pragma unroll
    for (int m = 0; m < 4; ++m)
#pragma unroll
      for (int n = 0; n < 4; ++n)
        acc[m][n] = mfma16(a[m], b[n], acc[m][n]);
    __syncthreads();
  }
  int tg0 = (bm * 128 + wr * 64) & 4095;
  int bb  = (bm * 128) >> 12;
  if (wc == 0) {                                   // K head: RMS + RoPE
    float w0 = kw[lo], w1 = kw[16 + lo], w2 = kw[32 + lo], w3 = kw[48 + lo];
    const float2* tb = (const float2*)trig;
#pragma unroll
    for (int m = 0; m < 4; ++m)
#pragma unroll
      for (int r = 0; r < 4; ++r) {
        float x0 = acc[m][0][r], x1 = acc[m][1][r];
        float x2 = acc[m][2][r], x3 = acc[m][3][r];
        float ss = x0 * x0 + x1 * x1 + x2 * x2 + x3 * x3;
        ss += __shfl_xor(ss, 1); ss += __shfl_xor(ss, 2);
        ss += __shfl_xor(ss, 4); ss += __shfl_xor(ss, 8);
        float rn = rsqrtf(ss * 0.015625f + 1e-6f);
        x0 *= rn * w0; x1 *= rn * w1; x2 *= rn * w2; x3 *= rn * w3;
        int tp = tg0 + m * 16 + hi * 4 + r;
        float2 cs0 = tb[tp * 32 + lo];
        float2 cs1 = tb[tp * 32 + 16 + lo];
        float o0 = x0 * cs0.x - x2 * cs0.y;
        float o1 = x1 * cs1.x - x3 * cs1.y;
        float o2 = x2 * cs0.x + x0 * cs0.y;
        float o3 = x3 * cs1.x + x1 * cs1.y;
        size_t tb_ = ((size_t)bb * 4096 + tp) * 64;
        kb2[tb_ + lo]      = (short)f2bf(o0);
        kb2[tb_ + 16 + lo] = (short)f2bf(o1);
        kb2[tb_ + 32 + lo] = (short)f2bf(o2);
        kb2[tb_ + 48 + lo] = (short)f2bf(o3);
      }
  } else {                                         // V: transpose to [d][t]
#pragma unroll
    for (int m = 0; m < 4; ++m)
#pragma unroll
      for (int nf = 0; nf < 4; ++nf) {
        int dd = nf * 16 + lo;
        short4 o;
        o.x = (short)f2bf(acc[m][nf][0]);
        o.y = (short)f2bf(acc[m][nf][1]);
        o.z = (short)f2bf(acc[m][nf][2]);
        o.w = (short)f2bf(acc[m][nf][3]);
        *(short4*)&vtg[((size_t)(bb * 64 + dd)) * 4096 + tg0 + m * 16 + hi * 4] = o;
      }
  }
}

// ---------------- kernel: 256x256x64 bf16 GEMM, 8-phase, all-asm sync -------
// Per K-tile (4 phases): ph0 rdA0-3+rdB0-1, stage(jt+1,A,h1,d^1); ph1 rdA4-7,
// stage(jt+1,B,h1,d^1); ph2 rdB2-3, stage(jt+2,A,h0,d); ph3 stage(jt+2,B,h0,d),
// VMCNT2. vmcnt(2) at each tile boundary leaves only {jt+2 A0,B0} in flight —
// tile jt+1 (incl. A1/B1 staged this iter) is forced-landed (race-fixed ledger).
// mode 1 (Q): fused RMS+RoPE epilogue, direct global stores -> qb2.
__global__ __launch_bounds__(512, 2) void k_gemm256(
    const short* __restrict__ A, const short* __restrict__ Bt,
    void* __restrict__ Cout, int M, int N, int K, int outBf16,
    const float* __restrict__ trig, const float* __restrict__ qw,
    short* __restrict__ qb2, int mode) {
  __shared__ short sm[65536];                       // 128 KiB
  int nbn = N >> 8;
  int nwg = (M >> 8) * nbn;
  int bid = blockIdx.x;
  int swz = (bid & 7) * (nwg >> 3) + (bid >> 3);    // XCD swizzle (nwg % 8 == 0)
  int bm = swz / nbn, bn = swz % nbn;
  int tid = threadIdx.x, wid = tid >> 6, lane = tid & 63;
  int wm = wid >> 2, wn = wid & 3;
  int lo = lane & 15, hi = lane >> 4;
  int NT = K >> 6;                                  // # K-tiles (BK=64)

  int r0 = tid >> 3, dc = tid & 7;
  int sc = dc ^ (r0 & 7);                           // pre-swizzled source chunk
  const short* aS0 = A  + (size_t)(bm * 256 + r0) * K + sc * 8;
  const short* bS0 = Bt + (size_t)(bn * 256 + r0) * K + sc * 8;
  size_t hstep = (size_t)128 * K;

  // stage one half-tile (mat, M-half h) of K-tile jt into dbuf d (2 gloads)
  auto stage = [&](int jt, int mat, int h, int d) {
    const short* s = (mat ? bS0 : aS0) + (size_t)h * hstep + jt * 64;
    short* l = sm + d * 32768 + mat * 16384 + h * 8192;
    gload16(s,                  l + tid * 8);
    gload16(s + (size_t)64 * K, l + 4096 + tid * 8);
  };

  unsigned smB = (unsigned)(unsigned long long)(void*)sm;
  unsigned aRdB[2];
#pragma unroll
  for (int kk = 0; kk < 2; ++kk)
    aRdB[kk] = (unsigned)(lo * 128 + (((kk << 2) | hi) ^ (lo & 7)) * 16);

  short8 Afr[8][2];
  short8 Bfr[4][2];
  f32x4 acc[8][4] = {};

  auto rdA = [&](int d, int m0) {
    unsigned base = smB + d * 65536 + wm * 16384;
#pragma unroll
    for (int m = 0; m < 4; ++m)
#pragma unroll
      for (int kk = 0; kk < 2; ++kk)
        Afr[m0 + m][kk] = dsr128(base + (m0 + m) * 2048 + aRdB[kk]);
  };
  auto rdB = [&](int d, int n0) {
    unsigned base = smB + d * 65536 + 32768 + (wn >> 1) * 16384 + (wn & 1) * 8192;
#pragma unroll
    for (int nf = 0; nf < 2; ++nf)
#pragma unroll
      for (int kk = 0; kk < 2; ++kk)
        Bfr[n0 + nf][kk] = dsr128(base + (n0 + nf) * 2048 + aRdB[kk]);
  };
  auto quad = [&](int m0, int n0) {                 // 16 MFMA
    __builtin_amdgcn_s_setprio(1);
#pragma unroll
    for (int m = 0; m < 4; ++m)
#pragma unroll
      for (int j = 0; j < 2; ++j)
#pragma unroll
        for (int kk = 0; kk < 2; ++kk)
          acc[m0 + m][n0 + j] = mfma16(Afr[m0 + m][kk], Bfr[n0 + j][kk],
                                       acc[m0 + m][n0 + j]);
    __builtin_amdgcn_s_setprio(0);
  };

  // prologue: tile0 all 4 halves (dbuf0) + tile1 A0,B0 (dbuf1) = 12 loads;
  // vmcnt(4) -> tile0 fully landed, tile1's 4 loads may remain in flight.
  stage(0, 0, 0, 0); stage(0, 1, 0, 0); stage(0, 0, 1, 0); stage(0, 1, 1, 0);
  if (NT > 1) { stage(1, 0, 0, 1); stage(1, 1, 0, 1); }
  VMCNT4;
  ASMBAR;

#pragma unroll 2
  for (int jt = 0; jt < NT; ++jt) {
    int d = jt & 1;
    // ph0
    rdA(d, 0); rdB(d, 0);
    if (jt + 1 < NT) stage(jt + 1, 0, 1, d ^ 1);
    ASMBAR; LGKM0; SCHED0;
    quad(0, 0);
    ASMBAR;
    // ph1
    rdA(d, 4);
    if (jt + 1 < NT) stage(jt + 1, 1, 1, d ^ 1);
    ASMBAR; LGKM0; SCHED0;
    quad(4, 0);
    ASMBAR;
    // ph2
    rdB(d, 2);
    if (jt + 2 < NT) stage(jt + 2, 0, 0, d);
    ASMBAR; LGKM0; SCHED0;
    quad(0, 2);
    ASMBAR;
    // ph3: counted vmcnt — forces tile jt+1 landed, keeps jt+2 A0,B0 in flight
    if (jt + 2 < NT) stage(jt + 2, 1, 0, d);
    VMCNT2;
    ASMBAR;
    quad(4, 2);
    ASMBAR;
  }

  if (mode == 1) {
    // ---- fused Q epilogue: RMS+RoPE, direct global stores (no LDS)
    int tg0 = (bm * 256 + wm * 128) & 4095;
    int bb  = (bm * 256) >> 12;
    int hh  = bn * 4 + wn;
    float w0 = qw[lo], w1 = qw[16 + lo], w2 = qw[32 + lo], w3 = qw[48 + lo];
    short* dst = qb2 + (size_t)((bb * 16 + hh) * 4096) * 64;
    const float2* tb = (const float2*)trig;
#pragma unroll
    for (int m = 0; m < 8; ++m)
#pragma unroll
      for (int r = 0; r < 4; ++r) {
        float x0 = acc[m][0][r], x1 = acc[m][1][r];
        float x2 = acc[m][2][r], x3 = acc[m][3][r];
        float ss = x0 * x0 + x1 * x1 + x2 * x2 + x3 * x3;
        ss += __shfl_xor(ss, 1); ss += __shfl_xor(ss, 2);
        ss += __shfl_xor(ss, 4); ss += __shfl_xor(ss, 8);
        float rn = rsqrtf(ss * 0.015625f + 1e-6f);
        x0 *= rn * w0; x1 *= rn * w1; x2 *= rn * w2; x3 *= rn * w3;
        int tp = tg0 + m * 16 + hi * 4 + r;
        float2 cs0 = tb[tp * 32 + lo];
        float2 cs1 = tb[tp * 32 + 16 + lo];
        float o0 = x0 * cs0.x - x2 * cs0.y;
        float o1 = x1 * cs1.x - x3 * cs1.y;
        float o2 = x2 * cs0.x + x0 * cs0.y;
        float o3 = x3 * cs1.x + x1 * cs1.y;
        size_t tb_ = (size_t)tp * 64;
        dst[tb_ + lo]      = (short)f2bf(o0);
        dst[tb_ + 16 + lo] = (short)f2bf(o1);
        dst[tb_ + 32 + lo] = (short)f2bf(o2);
        dst[tb_ + 48 + lo] = (short)f2bf(o3);
      }
    return;
  }

  // ---- mode 0: plain C write. layout col = lane&15, row = (lane>>4)*4 + reg
  int row0 = bm * 256 + wm * 128 + hi * 4;
  int col0 = bn * 256 + wn * 64 + lo;
  if (outBf16) {
    short* C = (short*)Cout;
#pragma unroll
    for (int m = 0; m < 8; ++m)
#pragma unroll
      for (int nf = 0; nf < 4; ++nf)
#pragma unroll
        for (int r = 0; r < 4; ++r)
          C[(size_t)(row0 + m * 16 + r) * N + col0 + nf * 16] = (short)f2bf(acc[m][nf][r]);
  } else {
    float* C = (float*)Cout;
#pragma unroll
    for (int m = 0; m < 8; ++m)
#pragma unroll
      for (int nf = 0; nf < 4; ++nf)
#pragma unroll
        for (int r = 0; r < 4; ++r)
          C[(size_t)(row0 + m * 16 + r) * N + col0 + nf * 16] = acc[m][nf][r];
  }
}

// ---------------- kernel: blocked sliding-window attention (swapped QK^T) ----
__global__ __launch_bounds__(256, 4) void k_attn(const short* __restrict__ qb,
                                                 const short* __restrict__ kb,
                                                 const short* __restrict__ vtg,
                                                 short* __restrict__ y) {
  __shared__ __align__(16) char smem[33792];
  short* ks  = (short*)smem;            // [128 key][64 d], chunk-XOR swizzled
  short* vts = (short*)(smem + 16384);  // [64 d][128 key], chunk-XOR swizzled
  int bid = blockIdx.x;
  int swz = (bid & 7) * 256 + (bid >> 3);          // XCD swizzle
  int h = swz & 15, n = (swz >> 4) & 31, b = swz >> 9;
  int tid = threadIdx.x, wid = tid >> 6, lane = tid & 63;
  int lo = lane & 31, hi = lane >> 5;

  const short* qrow = qb + (size_t)((b * 16 + h) * 4096 + n * 128 + wid * 32 + lo) * 64;
  short8 aq[4];
#pragma unroll
  for (int s = 0; s < 4; ++s) aq[s] = *(const short8*)(qrow + s * 16 + hi * 8);

  f32x16 O0 = {}, O1 = {};                         // O^T: rows d / d+32, col q
  float mrun = -1e30f, lrun = 0.f;
  int qr = wid * 32 + lo;
  const float SC = 0.125f * 1.4426950408889634f;   // scale * log2(e)

  for (int hf = (n == 0) ? 1 : 0; hf < 2; ++hf) {  // n==0: half0 fully masked
    int tg = (n - 1 + hf) * 128;                   // first key token (within b)
#pragma unroll
    for (int p = 0; p < 4; ++p) {
      int idx = p * 256 + tid;
      int r = idx >> 3, dc = idx & 7;
      gload16(kb + (size_t)(b * 4096 + tg + r) * 64 + ((dc ^ (r & 7)) << 3),
              ks + idx * 8);
    }
#pragma unroll
    for (int p = 0; p < 4; ++p) {
      int idx = p * 256 + tid;
      int dd = idx >> 4, s = idx & 15;
      gload16(vtg + (size_t)(b * 64 + dd) * 4096 + tg + ((s ^ (dd & 7)) << 3),
              vts + idx * 8);
    }
    __syncthreads();

#pragma unroll
    for (int mt = 0; mt < 4; ++mt) {
      f32x16 S = {};
      int r = mt * 32 + lo;
#pragma unroll
      for (int kst = 0; kst < 4; ++kst) {
        short8 kf = *(const short8*)&ks[r * 64 + ((((kst << 1) | hi) ^ (r & 7)) << 3)];
        S = mfma32(kf, aq[kst], S);
      }
#pragma unroll
      for (int rr = 0; rr < 16; ++rr) {
        int kg = hf * 128 + mt * 32 + (rr & 3) + ((rr >> 2) << 3) + (hi << 2);
        S[rr] = (kg >= qr && kg <= qr + 128) ? S[rr] * SC : -30000.f;
      }
      float pmax = S[0];
#pragma unroll
      for (int rr = 1; rr < 16; ++rr) pmax = fmaxf(pmax, S[rr]);
      pmax = fmaxf(pmax, __shfl_xor(pmax, 32));
      if (!__all(pmax - mrun <= 8.f)) {
        float mn = fmaxf(mrun, pmax);
        float al = exp2f(mrun - mn);
        lrun *= al; mrun = mn;
#pragma unroll
        for (int rr = 0; rr < 16; ++rr) { O0[rr] *= al; O1[rr] *= al; }
      }
      float ls = 0.f;
#pragma unroll
      for (int rr = 0; rr < 16; ++rr) { S[rr] = exp2f(S[rr] - mrun); ls += S[rr]; }
      ls += __shfl_xor(ls, 32);
      lrun += ls;
#pragma unroll
      for (int h2 = 0; h2 < 2; ++h2) {
        int b0 = h2 * 8;
        unsigned pk0 = cvtpk(S[b0 + 0], S[b0 + 1]);
        unsigned pk1 = cvtpk(S[b0 + 2], S[b0 + 3]);
        unsigned pk2 = cvtpk(S[b0 + 4], S[b0 + 5]);
        unsigned pk3 = cvtpk(S[b0 + 6], S[b0 + 7]);
        asm("v_permlane32_swap_b32 %0, %1" : "+v"(pk0), "+v"(pk2));
        asm("v_permlane32_swap_b32 %0, %1" : "+v"(pk1), "+v"(pk3));
        uint4v uw; uw.x = pk0; uw.y = pk1; uw.z = pk2; uw.w = pk3;
        short8 pb = __builtin_bit_cast(short8, uw);
        int kc = mt * 4 + h2 * 2 + hi;
        short8 vb0 = *(const short8*)&vts[lo * 128 + ((kc ^ (lo & 7)) << 3)];
        short8 vb1 = *(const short8*)&vts[(32 + lo) * 128 + ((kc ^ (lo & 7)) << 3)];
        O0 = mfma32(vb0, pb, O0);
        O1 = mfma32(vb1, pb, O1);
      }
    }
    __syncthreads();
  }

  float inv = 1.f / lrun;
  float* ot = (float*)smem + wid * 2112;           // [64 d][33] per wave
#pragma unroll
  for (int r = 0; r < 16; ++r) {
    int d0 = (r & 3) + ((r >> 2) << 3) + (hi << 2);
    ot[d0 * 33 + lo]        = O0[r] * inv;
    ot[(d0 + 32) * 33 + lo] = O1[r] * inv;
  }
  __syncthreads();
  int tok = lane >> 3, dc = lane & 7;
#pragma unroll
  for (int g = 0; g < 4; ++g) {
    int q = g * 8 + tok;
    short8 o8;
#pragma unroll
    for (int jj = 0; jj < 8; ++jj)
      o8[jj] = (short)f2bf(ot[(dc * 8 + jj) * 33 + q]);
    *(short8*)&y[(size_t)(b * 4096 + n * 128 + wid * 32 + q) * 1024 + h * 64 + dc * 8] = o8;
  }
}

// ---------------- launch ----------------
extern "C" void kernel_launch(void* const* d_in, const int* in_sizes, int n_in,
                              void* d_out, int out_size, void* d_ws, size_t ws_size,
                              hipStream_t stream) {
  const float* x      = (const float*)d_in[0];
  const int*   pos    = (const int*)d_in[1];
  const float* w_attn = (const float*)d_in[2];
  const float* w_proj = (const float*)d_in[3];
  const float* qw     = (const float*)d_in[4];
  const float* kw     = (const float*)d_in[5];

  char* ws = (char*)d_ws;
  short* xb   = (short*)ws;                         // 33,554,432 B (aliased as y later)
  short* wabt = (short*)(ws + 33554432);            //  2,359,296 B (1152 x 1024)
  short* wpbt = (short*)(ws + 35913728);            //  2,097,152 B
  short* qb2  = (short*)(ws + 38010880);            // 33,554,432 B
  short* kb2  = (short*)(ws + 71565312);            //  2,097,152 B
  short* vtg  = (short*)(ws + 73662464);            //  2,097,152 B
  float* trig = (float*)(ws + 75759616);            //  1,048,576 B (cos,sin pairs)
  short* ybuf = xb;                                 // xb dead after Q/KV GEMMs

  hipLaunchKernelGGL(k_prep, dim3(16384 + 1152 + 1024 + 512), dim3(256), 0, stream,
                     x, xb, w_attn, wabt, w_proj, wpbt, pos, trig);
  hipLaunchKernelGGL(k_gemmkv, dim3(128), dim3(256), 0, stream, xb,
                     wabt + (size_t)1024 * 1024, trig, kw, kb2, vtg);
  hipLaunchKernelGGL(k_gemm256, dim3(256), dim3(512), 0, stream, xb, wabt,
                     (void*)nullptr, 16384, 1024, 1024, 1, trig, qw, qb2, 1);
  hipLaunchKernelGGL(k_attn, dim3(2048), dim3(256), 0, stream, qb2, kb2, vtg, ybuf);
  hipLaunchKernelGGL(k_gemm256, dim3(256), dim3(512), 0, stream, ybuf, wpbt, d_out,
                     16384, 1024, 1024, 0,
                     (const float*)nullptr, (const float*)nullptr,
                     (short*)nullptr, 0);
}

// Round 12
// 160.751 us; speedup vs baseline: 1.0251x; 1.0251x over previous
//
#include <hip/hip_runtime.h>

// MQA fused layer, MI355X gfx950.
// B=4 T=4096 C=1024 H=16 D=64 W=128 NB=32.
// Pipeline: prep (cvt x, transpose-cvt weights, trig table — one dispatch) |
//           KV-GEMM 128^2 (fused RMS+RoPE K / V-transpose epilogue) |
//           Q-GEMM 256x128-tile 2-blocks/CU (fused RMS+RoPE epilogue) |
//           blocked sliding-window attention | proj GEMM 256x128 -> d_out.

typedef __attribute__((ext_vector_type(8))) short short8;
typedef __attribute__((ext_vector_type(4))) float f32x4;
typedef __attribute__((ext_vector_type(16))) float f32x16;
typedef __attribute__((ext_vector_type(4))) unsigned uint4v;

#define DEV static __device__ __forceinline__

DEV unsigned short f2bf(float f) {           // fp32 -> bf16 RNE
  unsigned u = __builtin_bit_cast(unsigned, f);
  u += 0x7fffu + ((u >> 16) & 1u);
  return (unsigned short)(u >> 16);
}
DEV float bf2f(unsigned short s) {
  unsigned u = ((unsigned)s) << 16;
  return __builtin_bit_cast(float, u);
}
DEV unsigned cvtpk(float a, float b) {       // {bf16(a), bf16(b)} packed
  unsigned r;
  asm("v_cvt_pk_bf16_f32 %0, %1, %2" : "=v"(r) : "v"(a), "v"(b));
  return r;
}

DEV f32x4 mfma16(short8 a, short8 b, f32x4 c) {
  return __builtin_amdgcn_mfma_f32_16x16x32_bf16(a, b, c, 0, 0, 0);
}
DEV f32x16 mfma32(short8 a, short8 b, f32x16 c) {
  return __builtin_amdgcn_mfma_f32_32x32x16_bf16(a, b, c, 0, 0, 0);
}

// async global->LDS, 16B per lane
DEV void gload16(const void* g, void* l) {
  __builtin_amdgcn_global_load_lds(
      (const __attribute__((address_space(1))) unsigned int*)(unsigned long long)g,
      (__attribute__((address_space(3))) unsigned int*)(unsigned int)(unsigned long long)l,
      16, 0, 0);
}

// ---------------- kernel: merged prep (cvt x | tcvt w_attn | tcvt w_proj |
//                  trig table) — one dispatch, branch by block range ----------
__global__ __launch_bounds__(256) void k_prep(const float* __restrict__ x,
                                              short* __restrict__ xb,
                                              const float* __restrict__ wa,
                                              short* __restrict__ wabt,
                                              const float* __restrict__ wp,
                                              short* __restrict__ wpbt,
                                              const int* __restrict__ pos,
                                              float* __restrict__ trig) {
  __shared__ float tl[32][33];
  int bid = blockIdx.x, tid = threadIdx.x;
  if (bid < 16384) {                                 // cvt x -> bf16
    int i = bid * 256 + tid;
    float4 v = ((const float4*)x)[i];
    short4 o;
    o.x = (short)f2bf(v.x); o.y = (short)f2bf(v.y);
    o.z = (short)f2bf(v.z); o.w = (short)f2bf(v.w);
    ((short4*)xb)[i] = o;
    return;
  }
  if (bid < 16384 + 1152 + 1024) {                   // transpose-cvt weights
    const float* W; short* Wt; int N, local;
    if (bid < 16384 + 1152) { local = bid - 16384; W = wa; Wt = wabt; N = 1152; }
    else { local = bid - 16384 - 1152; W = wp; Wt = wpbt; N = 1024; }
    int k0 = (local & 31) * 32, n0 = (local >> 5) * 32;
    int tx = tid & 31, ty = tid >> 5;
#pragma unroll
    for (int i = 0; i < 4; ++i)
      tl[ty + i * 8][tx] = W[(size_t)(k0 + ty + i * 8) * N + n0 + tx];
    __syncthreads();
#pragma unroll
    for (int i = 0; i < 4; ++i)
      Wt[(size_t)(n0 + ty + i * 8) * 1024 + k0 + tx] = (short)f2bf(tl[tx][ty + i * 8]);
    return;
  }
  {                                                  // trig table [4096][32]
    int idx = (bid - 16384 - 1152 - 1024) * 256 + tid;
    int t = idx >> 5, j = idx & 31;
    float invf = __expf((float)j * (-13.815510558f / 32.f));
    float p = (float)pos[t * 3 + (j % 3)];
    float s, c;
    sincosf(p * invf, &s, &c);
    ((float2*)trig)[idx] = make_float2(c, s);
  }
}

// ---------------- kernel: KV GEMM 128x128 (m97 structure) + fused epilogue --
__global__ __launch_bounds__(256) void k_gemmkv(const short* __restrict__ A,
                                                const short* __restrict__ Bt,
                                                const float* __restrict__ trig,
                                                const float* __restrict__ kw,
                                                short* __restrict__ kb2,
                                                short* __restrict__ vtg) {
  __shared__ short As[128 * 32];
  __shared__ short Bs[128 * 32];
  const int K = 1024;
  int bid = blockIdx.x;
  int bm = (bid & 7) * 16 + (bid >> 3);            // XCD swizzle, nwg=128
  int tid = threadIdx.x, lane = tid & 63, wid = tid >> 6;
  int wr = wid >> 1, wc = wid & 1;
  int lo = lane & 15, hi = lane >> 4;
  const short* Ab = A + (size_t)(bm * 128 + (tid >> 2)) * K + (tid & 3) * 8;
  const short* Bb = Bt + (size_t)(tid >> 2) * K + (tid & 3) * 8;
  f32x4 acc[4][4] = {};
  for (int kt = 0; kt < K; kt += 32) {
    gload16(Ab + kt,            As + tid * 8);
    gload16(Ab + kt + 64 * K,   As + 2048 + tid * 8);
    gload16(Bb + kt,            Bs + tid * 8);
    gload16(Bb + kt + 64 * K,   Bs + 2048 + tid * 8);
    __syncthreads();
    short8 a[4], b[4];
#pragma unroll
    for (int m = 0; m < 4; ++m)
      a[m] = *(const short8*)&As[(wr * 64 + m * 16 + lo) * 32 + hi * 8];
#pragma unroll
    for (int n = 0; n < 4; ++n)
      b[n] = *(const short8*)&Bs[(wc * 64 + n * 16 + lo) * 32 + hi * 8];
#pragma unroll
    for (int m = 0; m < 4; ++m)
#pragma unroll
      for (int n = 0; n < 4; ++n)
        acc[m][n] = mfma16(a[m], b[n], acc[m][n]);
    __syncthreads();
  }
  int tg0 = (bm * 128 + wr * 64) & 4095;
  int bb  = (bm * 128) >> 12;
  if (wc == 0) {                                   // K head: RMS + RoPE
    float w0 = kw[lo], w1 = kw[16 + lo], w2 = kw[32 + lo], w3 = kw[48 + lo];
    const float2* tb = (const float2*)trig;
#pragma unroll
    for (int m = 0; m < 4; ++m)
#pragma unroll
      for (int r = 0; r < 4; ++r) {
        float x0 = acc[m][0][r], x1 = acc[m][1][r];
        float x2 = acc[m][2][r], x3 = acc[m][3][r];
        float ss = x0 * x0 + x1 * x1 + x2 * x2 + x3 * x3;
        ss += __shfl_xor(ss, 1); ss += __shfl_xor(ss, 2);
        ss += __shfl_xor(ss, 4); ss += __shfl_xor(ss, 8);
        float rn = rsqrtf(ss * 0.015625f + 1e-6f);
        x0 *= rn * w0; x1 *= rn * w1; x2 *= rn * w2; x3 *= rn * w3;
        int tp = tg0 + m * 16 + hi * 4 + r;
        float2 cs0 = tb[tp * 32 + lo];
        float2 cs1 = tb[tp * 32 + 16 + lo];
        float o0 = x0 * cs0.x - x2 * cs0.y;
        float o1 = x1 * cs1.x - x3 * cs1.y;
        float o2 = x2 * cs0.x + x0 * cs0.y;
        float o3 = x3 * cs1.x + x1 * cs1.y;
        size_t tb_ = ((size_t)bb * 4096 + tp) * 64;
        kb2[tb_ + lo]      = (short)f2bf(o0);
        kb2[tb_ + 16 + lo] = (short)f2bf(o1);
        kb2[tb_ + 32 + lo] = (short)f2bf(o2);
        kb2[tb_ + 48 + lo] = (short)f2bf(o3);
      }
  } else {                                         // V: transpose to [d][t]
#pragma unroll
    for (int m = 0; m < 4; ++m)
#pragma unroll
      for (int nf = 0; nf < 4; ++nf) {
        int dd = nf * 16 + lo;
        short4 o;
        o.x = (short)f2bf(acc[m][nf][0]);
        o.y = (short)f2bf(acc[m][nf][1]);
        o.z = (short)f2bf(acc[m][nf][2]);
        o.w = (short)f2bf(acc[m][nf][3]);
        *(short4*)&vtg[((size_t)(bb * 64 + dd)) * 4096 + tg0 + m * 16 + hi * 4] = o;
      }
  }
}

// ---------------- kernel: 256Mx128N bf16 GEMM, 2 blocks/CU ------------------
// 4 waves (2M x 2N), per-wave C = 128x64 (same inner structure as before).
// LDS 48 KB single-buffered -> with ~248 total regs/wave, 2 blocks co-reside
// per CU; grid 512 = all blocks resident. Simple stage->sync->compute->sync;
// the sibling block's waves cover each block's DMA-drain stall (m114 overlap).
// mode 1 (Q): fused RMS+RoPE epilogue, head = bn*2 + wn.
__global__ __launch_bounds__(256, 2) void k_gemmbig(
    const short* __restrict__ A, const short* __restrict__ Bt,
    void* __restrict__ Cout, int M, int N, int K, int outBf16,
    const float* __restrict__ trig, const float* __restrict__ qw,
    short* __restrict__ qb2, int mode) {
  __shared__ short sm[24576];                       // A 32 KB + B 16 KB
  int nbn = N >> 7;                                 // N-tiles of 128
  int nwg = (M >> 8) * nbn;
  int bid = blockIdx.x;
  int swz = (bid & 7) * (nwg >> 3) + (bid >> 3);    // XCD swizzle (nwg % 8 == 0)
  int bm = swz / nbn, bn = swz % nbn;
  int tid = threadIdx.x, wid = tid >> 6, lane = tid & 63;
  int wm = wid >> 1, wn = wid & 1;
  int lo = lane & 15, hi = lane >> 4;
  int NT = K >> 6;                                  // BK = 64

  // staging: thread t covers slots t + k*256; row = (t>>3)+32k, chunk = t&7.
  // 32k preserves row&7 -> swizzled source chunk sc is k-invariant.
  int r0 = tid >> 3, ch = tid & 7;
  int sc = ch ^ (r0 & 7);
  const short* aS0 = A  + (size_t)(bm * 256 + r0) * K + sc * 8;
  const short* bS0 = Bt + (size_t)(bn * 128 + r0) * K + sc * 8;

  int aRd[2];                                       // frag chunk byte offsets
#pragma unroll
  for (int kk = 0; kk < 2; ++kk)
    aRd[kk] = (((kk << 2) | hi) ^ (lo & 7)) * 8;    // element offset in row

  short8 Afr[8][2];
  short8 Bfr[4][2];
  f32x4 acc[8][4] = {};

  auto rdA = [&](int m0) {
#pragma unroll
    for (int m = 0; m < 4; ++m)
#pragma unroll
      for (int kk = 0; kk < 2; ++kk)
        Afr[m0 + m][kk] =
            *(const short8*)&sm[(wm * 128 + (m0 + m) * 16 + lo) * 64 + aRd[kk]];
  };
  auto rdB = [&]() {
#pragma unroll
    for (int nf = 0; nf < 4; ++nf)
#pragma unroll
      for (int kk = 0; kk < 2; ++kk)
        Bfr[nf][kk] =
            *(const short8*)&sm[16384 + (wn * 64 + nf * 16 + lo) * 64 + aRd[kk]];
  };
  auto quad = [&](int m0, int n0) {                 // 16 MFMA
    __builtin_amdgcn_s_setprio(1);
#pragma unroll
    for (int m = 0; m < 4; ++m)
#pragma unroll
      for (int j = 0; j < 2; ++j)
#pragma unroll
        for (int kk = 0; kk < 2; ++kk)
          acc[m0 + m][n0 + j] = mfma16(Afr[m0 + m][kk], Bfr[n0 + j][kk],
                                       acc[m0 + m][n0 + j]);
    __builtin_amdgcn_s_setprio(0);
  };

  for (int jt = 0; jt < NT; ++jt) {
#pragma unroll
    for (int k = 0; k < 8; ++k)                     // A: 256x64 = 32 KB
      gload16(aS0 + jt * 64 + (size_t)32 * k * K, sm + (tid + k * 256) * 8);
#pragma unroll
    for (int k = 0; k < 4; ++k)                     // B: 128x64 = 16 KB
      gload16(bS0 + jt * 64 + (size_t)32 * k * K,
              sm + 16384 + (tid + k * 256) * 8);
    __syncthreads();                                // DMA drained (implicit vmcnt0)
    rdA(0); rdB(); rdA(4);
    quad(0, 0); quad(0, 2); quad(4, 0); quad(4, 2);
    __syncthreads();                                // reads done before next stage
  }

  if (mode == 1) {
    // ---- fused Q epilogue: RMS+RoPE, direct global stores (no LDS)
    int tg0 = (bm * 256 + wm * 128) & 4095;
    int bb  = (bm * 256) >> 12;
    int hh  = bn * 2 + wn;                           // head 0..15
    float w0 = qw[lo], w1 = qw[16 + lo], w2 = qw[32 + lo], w3 = qw[48 + lo];
    short* dst = qb2 + (size_t)((bb * 16 + hh) * 4096) * 64;
    const float2* tb = (const float2*)trig;
#pragma unroll
    for (int m = 0; m < 8; ++m)
#pragma unroll
      for (int r = 0; r < 4; ++r) {
        float x0 = acc[m][0][r], x1 = acc[m][1][r];
        float x2 = acc[m][2][r], x3 = acc[m][3][r];
        float ss = x0 * x0 + x1 * x1 + x2 * x2 + x3 * x3;
        ss += __shfl_xor(ss, 1); ss += __shfl_xor(ss, 2);
        ss += __shfl_xor(ss, 4); ss += __shfl_xor(ss, 8);
        float rn = rsqrtf(ss * 0.015625f + 1e-6f);
        x0 *= rn * w0; x1 *= rn * w1; x2 *= rn * w2; x3 *= rn * w3;
        int tp = tg0 + m * 16 + hi * 4 + r;
        float2 cs0 = tb[tp * 32 + lo];
        float2 cs1 = tb[tp * 32 + 16 + lo];
        float o0 = x0 * cs0.x - x2 * cs0.y;
        float o1 = x1 * cs1.x - x3 * cs1.y;
        float o2 = x2 * cs0.x + x0 * cs0.y;
        float o3 = x3 * cs1.x + x1 * cs1.y;
        size_t tb_ = (size_t)tp * 64;
        dst[tb_ + lo]      = (short)f2bf(o0);
        dst[tb_ + 16 + lo] = (short)f2bf(o1);
        dst[tb_ + 32 + lo] = (short)f2bf(o2);
        dst[tb_ + 48 + lo] = (short)f2bf(o3);
      }
    return;
  }

  // ---- mode 0: plain C write. layout col = lane&15, row = (lane>>4)*4 + reg
  int row0 = bm * 256 + wm * 128 + hi * 4;
  int col0 = bn * 128 + wn * 64 + lo;
  if (outBf16) {
    short* C = (short*)Cout;
#pragma unroll
    for (int m = 0; m < 8; ++m)
#pragma unroll
      for (int nf = 0; nf < 4; ++nf)
#pragma unroll
        for (int r = 0; r < 4; ++r)
          C[(size_t)(row0 + m * 16 + r) * N + col0 + nf * 16] = (short)f2bf(acc[m][nf][r]);
  } else {
    float* C = (float*)Cout;
#pragma unroll
    for (int m = 0; m < 8; ++m)
#pragma unroll
      for (int nf = 0; nf < 4; ++nf)
#pragma unroll
        for (int r = 0; r < 4; ++r)
          C[(size_t)(row0 + m * 16 + r) * N + col0 + nf * 16] = acc[m][nf][r];
  }
}

// ---------------- kernel: blocked sliding-window attention (swapped QK^T) ----
__global__ __launch_bounds__(256, 4) void k_attn(const short* __restrict__ qb,
                                                 const short* __restrict__ kb,
                                                 const short* __restrict__ vtg,
                                                 short* __restrict__ y) {
  __shared__ __align__(16) char smem[33792];
  short* ks  = (short*)smem;            // [128 key][64 d], chunk-XOR swizzled
  short* vts = (short*)(smem + 16384);  // [64 d][128 key], chunk-XOR swizzled
  int bid = blockIdx.x;
  int swz = (bid & 7) * 256 + (bid >> 3);          // XCD swizzle
  int h = swz & 15, n = (swz >> 4) & 31, b = swz >> 9;
  int tid = threadIdx.x, wid = tid >> 6, lane = tid & 63;
  int lo = lane & 31, hi = lane >> 5;

  const short* qrow = qb + (size_t)((b * 16 + h) * 4096 + n * 128 + wid * 32 + lo) * 64;
  short8 aq[4];
#pragma unroll
  for (int s = 0; s < 4; ++s) aq[s] = *(const short8*)(qrow + s * 16 + hi * 8);

  f32x16 O0 = {}, O1 = {};                         // O^T: rows d / d+32, col q
  float mrun = -1e30f, lrun = 0.f;
  int qr = wid * 32 + lo;
  const float SC = 0.125f * 1.4426950408889634f;   // scale * log2(e)

  for (int hf = (n == 0) ? 1 : 0; hf < 2; ++hf) {  // n==0: half0 fully masked
    int tg = (n - 1 + hf) * 128;                   // first key token (within b)
#pragma unroll
    for (int p = 0; p < 4; ++p) {
      int idx = p * 256 + tid;
      int r = idx >> 3, dc = idx & 7;
      gload16(kb + (size_t)(b * 4096 + tg + r) * 64 + ((dc ^ (r & 7)) << 3),
              ks + idx * 8);
    }
#pragma unroll
    for (int p = 0; p < 4; ++p) {
      int idx = p * 256 + tid;
      int dd = idx >> 4, s = idx & 15;
      gload16(vtg + (size_t)(b * 64 + dd) * 4096 + tg + ((s ^ (dd & 7)) << 3),
              vts + idx * 8);
    }
    __syncthreads();

#pragma unroll
    for (int mt = 0; mt < 4; ++mt) {
      f32x16 S = {};
      int r = mt * 32 + lo;
#pragma unroll
      for (int kst = 0; kst < 4; ++kst) {
        short8 kf = *(const short8*)&ks[r * 64 + ((((kst << 1) | hi) ^ (r & 7)) << 3)];
        S = mfma32(kf, aq[kst], S);
      }
#pragma unroll
      for (int rr = 0; rr < 16; ++rr) {
        int kg = hf * 128 + mt * 32 + (rr & 3) + ((rr >> 2) << 3) + (hi << 2);
        S[rr] = (kg >= qr && kg <= qr + 128) ? S[rr] * SC : -30000.f;
      }
      float pmax = S[0];
#pragma unroll
      for (int rr = 1; rr < 16; ++rr) pmax = fmaxf(pmax, S[rr]);
      pmax = fmaxf(pmax, __shfl_xor(pmax, 32));
      if (!__all(pmax - mrun <= 8.f)) {
        float mn = fmaxf(mrun, pmax);
        float al = exp2f(mrun - mn);
        lrun *= al; mrun = mn;
#pragma unroll
        for (int rr = 0; rr < 16; ++rr) { O0[rr] *= al; O1[rr] *= al; }
      }
      float ls = 0.f;
#pragma unroll
      for (int rr = 0; rr < 16; ++rr) { S[rr] = exp2f(S[rr] - mrun); ls += S[rr]; }
      ls += __shfl_xor(ls, 32);
      lrun += ls;
#pragma unroll
      for (int h2 = 0; h2 < 2; ++h2) {
        int b0 = h2 * 8;
        unsigned pk0 = cvtpk(S[b0 + 0], S[b0 + 1]);
        unsigned pk1 = cvtpk(S[b0 + 2], S[b0 + 3]);
        unsigned pk2 = cvtpk(S[b0 + 4], S[b0 + 5]);
        unsigned pk3 = cvtpk(S[b0 + 6], S[b0 + 7]);
        asm("v_permlane32_swap_b32 %0, %1" : "+v"(pk0), "+v"(pk2));
        asm("v_permlane32_swap_b32 %0, %1" : "+v"(pk1), "+v"(pk3));
        uint4v uw; uw.x = pk0; uw.y = pk1; uw.z = pk2; uw.w = pk3;
        short8 pb = __builtin_bit_cast(short8, uw);
        int kc = mt * 4 + h2 * 2 + hi;
        short8 vb0 = *(const short8*)&vts[lo * 128 + ((kc ^ (lo & 7)) << 3)];
        short8 vb1 = *(const short8*)&vts[(32 + lo) * 128 + ((kc ^ (lo & 7)) << 3)];
        O0 = mfma32(vb0, pb, O0);
        O1 = mfma32(vb1, pb, O1);
      }
    }
    __syncthreads();
  }

  float inv = 1.f / lrun;
  float* ot = (float*)smem + wid * 2112;           // [64 d][33] per wave
#pragma unroll
  for (int r = 0; r < 16; ++r) {
    int d0 = (r & 3) + ((r >> 2) << 3) + (hi << 2);
    ot[d0 * 33 + lo]        = O0[r] * inv;
    ot[(d0 + 32) * 33 + lo] = O1[r] * inv;
  }
  __syncthreads();
  int tok = lane >> 3, dc = lane & 7;
#pragma unroll
  for (int g = 0; g < 4; ++g) {
    int q = g * 8 + tok;
    short8 o8;
#pragma unroll
    for (int jj = 0; jj < 8; ++jj)
      o8[jj] = (short)f2bf(ot[(dc * 8 + jj) * 33 + q]);
    *(short8*)&y[(size_t)(b * 4096 + n * 128 + wid * 32 + q) * 1024 + h * 64 + dc * 8] = o8;
  }
}

// ---------------- launch ----------------
extern "C" void kernel_launch(void* const* d_in, const int* in_sizes, int n_in,
                              void* d_out, int out_size, void* d_ws, size_t ws_size,
                              hipStream_t stream) {
  const float* x      = (const float*)d_in[0];
  const int*   pos    = (const int*)d_in[1];
  const float* w_attn = (const float*)d_in[2];
  const float* w_proj = (const float*)d_in[3];
  const float* qw     = (const float*)d_in[4];
  const float* kw     = (const float*)d_in[5];

  char* ws = (char*)d_ws;
  short* xb   = (short*)ws;                         // 33,554,432 B (aliased as y later)
  short* wabt = (short*)(ws + 33554432);            //  2,359,296 B (1152 x 1024)
  short* wpbt = (short*)(ws + 35913728);            //  2,097,152 B
  short* qb2  = (short*)(ws + 38010880);            // 33,554,432 B
  short* kb2  = (short*)(ws + 71565312);            //  2,097,152 B
  short* vtg  = (short*)(ws + 73662464);            //  2,097,152 B
  float* trig = (float*)(ws + 75759616);            //  1,048,576 B (cos,sin pairs)
  short* ybuf = xb;                                 // xb dead after Q/KV GEMMs

  hipLaunchKernelGGL(k_prep, dim3(16384 + 1152 + 1024 + 512), dim3(256), 0, stream,
                     x, xb, w_attn, wabt, w_proj, wpbt, pos, trig);
  hipLaunchKernelGGL(k_gemmkv, dim3(128), dim3(256), 0, stream, xb,
                     wabt + (size_t)1024 * 1024, trig, kw, kb2, vtg);
  hipLaunchKernelGGL(k_gemmbig, dim3(512), dim3(256), 0, stream, xb, wabt,
                     (void*)nullptr, 16384, 1024, 1024, 1, trig, qw, qb2, 1);
  hipLaunchKernelGGL(k_attn, dim3(2048), dim3(256), 0, stream, qb2, kb2, vtg, ybuf);
  hipLaunchKernelGGL(k_gemmbig, dim3(512), dim3(256), 0, stream, ybuf, wpbt, d_out,
                     16384, 1024, 1024, 0,
                     (const float*)nullptr, (const float*)nullptr,
                     (short*)nullptr, 0);
}

// Round 13
// 159.482 us; speedup vs baseline: 1.0332x; 1.0080x over previous
//
#include <hip/hip_runtime.h>

// MQA fused layer, MI355X gfx950.
// B=4 T=4096 C=1024 H=16 D=64 W=128 NB=32.
// Pipeline: prep (cvt x, transpose-cvt weights, trig table — one dispatch) |
//           merged GEMM dispatch: blocks 0-127 KV-GEMM 128^2 (fused RMS+RoPE K
//           / V-transpose), blocks 128-639 Q-GEMM 256x128 (fused RMS+RoPE) |
//           blocked sliding-window attention | proj GEMM 256x128 -> d_out.

typedef __attribute__((ext_vector_type(8))) short short8;
typedef __attribute__((ext_vector_type(4))) float f32x4;
typedef __attribute__((ext_vector_type(16))) float f32x16;
typedef __attribute__((ext_vector_type(4))) unsigned uint4v;

#define DEV static __device__ __forceinline__

DEV unsigned short f2bf(float f) {           // fp32 -> bf16 RNE
  unsigned u = __builtin_bit_cast(unsigned, f);
  u += 0x7fffu + ((u >> 16) & 1u);
  return (unsigned short)(u >> 16);
}
DEV float bf2f(unsigned short s) {
  unsigned u = ((unsigned)s) << 16;
  return __builtin_bit_cast(float, u);
}
DEV unsigned cvtpk(float a, float b) {       // {bf16(a), bf16(b)} packed
  unsigned r;
  asm("v_cvt_pk_bf16_f32 %0, %1, %2" : "=v"(r) : "v"(a), "v"(b));
  return r;
}

DEV f32x4 mfma16(short8 a, short8 b, f32x4 c) {
  return __builtin_amdgcn_mfma_f32_16x16x32_bf16(a, b, c, 0, 0, 0);
}
DEV f32x16 mfma32(short8 a, short8 b, f32x16 c) {
  return __builtin_amdgcn_mfma_f32_32x32x16_bf16(a, b, c, 0, 0, 0);
}

// async global->LDS, 16B per lane
DEV void gload16(const void* g, void* l) {
  __builtin_amdgcn_global_load_lds(
      (const __attribute__((address_space(1))) unsigned int*)(unsigned long long)g,
      (__attribute__((address_space(3))) unsigned int*)(unsigned int)(unsigned long long)l,
      16, 0, 0);
}

// ---------------- kernel: merged prep (cvt x | tcvt w_attn | tcvt w_proj |
//                  trig table) — one dispatch, branch by block range ----------
__global__ __launch_bounds__(256) void k_prep(const float* __restrict__ x,
                                              short* __restrict__ xb,
                                              const float* __restrict__ wa,
                                              short* __restrict__ wabt,
                                              const float* __restrict__ wp,
                                              short* __restrict__ wpbt,
                                              const int* __restrict__ pos,
                                              float* __restrict__ trig) {
  __shared__ float tl[32][33];
  int bid = blockIdx.x, tid = threadIdx.x;
  if (bid < 16384) {                                 // cvt x -> bf16
    int i = bid * 256 + tid;
    float4 v = ((const float4*)x)[i];
    short4 o;
    o.x = (short)f2bf(v.x); o.y = (short)f2bf(v.y);
    o.z = (short)f2bf(v.z); o.w = (short)f2bf(v.w);
    ((short4*)xb)[i] = o;
    return;
  }
  if (bid < 16384 + 1152 + 1024) {                   // transpose-cvt weights
    const float* W; short* Wt; int N, local;
    if (bid < 16384 + 1152) { local = bid - 16384; W = wa; Wt = wabt; N = 1152; }
    else { local = bid - 16384 - 1152; W = wp; Wt = wpbt; N = 1024; }
    int k0 = (local & 31) * 32, n0 = (local >> 5) * 32;
    int tx = tid & 31, ty = tid >> 5;
#pragma unroll
    for (int i = 0; i < 4; ++i)
      tl[ty + i * 8][tx] = W[(size_t)(k0 + ty + i * 8) * N + n0 + tx];
    __syncthreads();
#pragma unroll
    for (int i = 0; i < 4; ++i)
      Wt[(size_t)(n0 + ty + i * 8) * 1024 + k0 + tx] = (short)f2bf(tl[tx][ty + i * 8]);
    return;
  }
  {                                                  // trig table [4096][32]
    int idx = (bid - 16384 - 1152 - 1024) * 256 + tid;
    int t = idx >> 5, j = idx & 31;
    float invf = __expf((float)j * (-13.815510558f / 32.f));
    float p = (float)pos[t * 3 + (j % 3)];
    float s, c;
    sincosf(p * invf, &s, &c);
    ((float2*)trig)[idx] = make_float2(c, s);
  }
}

// ---------------- kernel: merged big GEMM dispatch --------------------------
// blocks 0..127   : KV GEMM 128x128 (m97 structure) + fused RMS+RoPE K / V^T.
// blocks 128..639 : Q GEMM 256Mx128N (2 blocks/CU) + fused RMS+RoPE epilogue
//                   (mode 1) or plain C write (mode 0, proj: grid 512, all Q).
__global__ __launch_bounds__(256, 2) void k_gemmbig(
    const short* __restrict__ A, const short* __restrict__ Bt,
    void* __restrict__ Cout, int M, int N, int K, int outBf16,
    const float* __restrict__ trig, const float* __restrict__ qw,
    short* __restrict__ qb2, int mode,
    const short* __restrict__ Btkv, const float* __restrict__ kw,
    short* __restrict__ kb2, short* __restrict__ vtg) {
  __shared__ short sm[24576];                       // 48 KB (KV path uses 16 KB)
  int tid = threadIdx.x, lane = tid & 63, wid = tid >> 6;

  if (mode == 1 && blockIdx.x < 128) {
    // ================= KV path (m97 128^2 structure) =================
    short* As = sm;                                  // 128x32 bf16 = 8 KB
    short* Bs = sm + 4096;                           // 8 KB
    const int Kk = 1024;
    int bid = blockIdx.x;
    int bm = (bid & 7) * 16 + (bid >> 3);            // XCD swizzle, nwg=128
    int wr = wid >> 1, wc = wid & 1;
    int lo = lane & 15, hi = lane >> 4;
    const short* Ab = A + (size_t)(bm * 128 + (tid >> 2)) * Kk + (tid & 3) * 8;
    const short* Bb = Btkv + (size_t)(tid >> 2) * Kk + (tid & 3) * 8;
    f32x4 acc[4][4] = {};
    for (int kt = 0; kt < Kk; kt += 32) {
      gload16(Ab + kt,             As + tid * 8);
      gload16(Ab + kt + 64 * Kk,   As + 2048 + tid * 8);
      gload16(Bb + kt,             Bs + tid * 8);
      gload16(Bb + kt + 64 * Kk,   Bs + 2048 + tid * 8);
      __syncthreads();
      short8 a[4], b[4];
#pragma unroll
      for (int m = 0; m < 4; ++m)
        a[m] = *(const short8*)&As[(wr * 64 + m * 16 + lo) * 32 + hi * 8];
#pragma unroll
      for (int n = 0; n < 4; ++n)
        b[n] = *(const short8*)&Bs[(wc * 64 + n * 16 + lo) * 32 + hi * 8];
#pragma unroll
      for (int m = 0; m < 4; ++m)
#pragma unroll
        for (int n = 0; n < 4; ++n)
          acc[m][n] = mfma16(a[m], b[n], acc[m][n]);
      __syncthreads();
    }
    int tg0 = (bm * 128 + wr * 64) & 4095;
    int bb  = (bm * 128) >> 12;
    if (wc == 0) {                                   // K head: RMS + RoPE
      float w0 = kw[lo], w1 = kw[16 + lo], w2 = kw[32 + lo], w3 = kw[48 + lo];
      const float2* tb = (const float2*)trig;
#pragma unroll
      for (int m = 0; m < 4; ++m)
#pragma unroll
        for (int r = 0; r < 4; ++r) {
          float x0 = acc[m][0][r], x1 = acc[m][1][r];
          float x2 = acc[m][2][r], x3 = acc[m][3][r];
          float ss = x0 * x0 + x1 * x1 + x2 * x2 + x3 * x3;
          ss += __shfl_xor(ss, 1); ss += __shfl_xor(ss, 2);
          ss += __shfl_xor(ss, 4); ss += __shfl_xor(ss, 8);
          float rn = rsqrtf(ss * 0.015625f + 1e-6f);
          x0 *= rn * w0; x1 *= rn * w1; x2 *= rn * w2; x3 *= rn * w3;
          int tp = tg0 + m * 16 + hi * 4 + r;
          float2 cs0 = tb[tp * 32 + lo];
          float2 cs1 = tb[tp * 32 + 16 + lo];
          float o0 = x0 * cs0.x - x2 * cs0.y;
          float o1 = x1 * cs1.x - x3 * cs1.y;
          float o2 = x2 * cs0.x + x0 * cs0.y;
          float o3 = x3 * cs1.x + x1 * cs1.y;
          size_t tb_ = ((size_t)bb * 4096 + tp) * 64;
          kb2[tb_ + lo]      = (short)f2bf(o0);
          kb2[tb_ + 16 + lo] = (short)f2bf(o1);
          kb2[tb_ + 32 + lo] = (short)f2bf(o2);
          kb2[tb_ + 48 + lo] = (short)f2bf(o3);
        }
    } else {                                         // V: transpose to [d][t]
#pragma unroll
      for (int m = 0; m < 4; ++m)
#pragma unroll
        for (int nf = 0; nf < 4; ++nf) {
          int dd = nf * 16 + lo;
          short4 o;
          o.x = (short)f2bf(acc[m][nf][0]);
          o.y = (short)f2bf(acc[m][nf][1]);
          o.z = (short)f2bf(acc[m][nf][2]);
          o.w = (short)f2bf(acc[m][nf][3]);
          *(short4*)&vtg[((size_t)(bb * 64 + dd)) * 4096 + tg0 + m * 16 + hi * 4] = o;
        }
    }
    return;
  }

  // ================= Q / proj path (256Mx128N, 2 blocks/CU) =================
  int nbn = N >> 7;                                 // N-tiles of 128
  int nwg = (M >> 8) * nbn;
  int bid = blockIdx.x - (mode == 1 ? 128 : 0);
  int swz = (bid & 7) * (nwg >> 3) + (bid >> 3);    // XCD swizzle (nwg % 8 == 0)
  int bm = swz / nbn, bn = swz % nbn;
  int wm = wid >> 1, wn = wid & 1;
  int lo = lane & 15, hi = lane >> 4;
  int NT = K >> 6;                                  // BK = 64

  int r0 = tid >> 3, ch = tid & 7;
  int sc = ch ^ (r0 & 7);                           // pre-swizzled source chunk
  const short* aS0 = A  + (size_t)(bm * 256 + r0) * K + sc * 8;
  const short* bS0 = Bt + (size_t)(bn * 128 + r0) * K + sc * 8;

  int aRd[2];                                       // frag chunk byte offsets
#pragma unroll
  for (int kk = 0; kk < 2; ++kk)
    aRd[kk] = (((kk << 2) | hi) ^ (lo & 7)) * 8;    // element offset in row

  short8 Afr[8][2];
  short8 Bfr[4][2];
  f32x4 acc[8][4] = {};

  auto rdA = [&](int m0) {
#pragma unroll
    for (int m = 0; m < 4; ++m)
#pragma unroll
      for (int kk = 0; kk < 2; ++kk)
        Afr[m0 + m][kk] =
            *(const short8*)&sm[(wm * 128 + (m0 + m) * 16 + lo) * 64 + aRd[kk]];
  };
  auto rdB = [&]() {
#pragma unroll
    for (int nf = 0; nf < 4; ++nf)
#pragma unroll
      for (int kk = 0; kk < 2; ++kk)
        Bfr[nf][kk] =
            *(const short8*)&sm[16384 + (wn * 64 + nf * 16 + lo) * 64 + aRd[kk]];
  };
  auto quad = [&](int m0, int n0) {                 // 16 MFMA
    __builtin_amdgcn_s_setprio(1);
#pragma unroll
    for (int m = 0; m < 4; ++m)
#pragma unroll
      for (int j = 0; j < 2; ++j)
#pragma unroll
        for (int kk = 0; kk < 2; ++kk)
          acc[m0 + m][n0 + j] = mfma16(Afr[m0 + m][kk], Bfr[n0 + j][kk],
                                       acc[m0 + m][n0 + j]);
    __builtin_amdgcn_s_setprio(0);
  };

  for (int jt = 0; jt < NT; ++jt) {
#pragma unroll
    for (int k = 0; k < 8; ++k)                     // A: 256x64 = 32 KB
      gload16(aS0 + jt * 64 + (size_t)32 * k * K, sm + (tid + k * 256) * 8);
#pragma unroll
    for (int k = 0; k < 4; ++k)                     // B: 128x64 = 16 KB
      gload16(bS0 + jt * 64 + (size_t)32 * k * K,
              sm + 16384 + (tid + k * 256) * 8);
    __syncthreads();                                // DMA drained (implicit vmcnt0)
    rdA(0); rdB(); rdA(4);
    quad(0, 0); quad(0, 2); quad(4, 0); quad(4, 2);
    __syncthreads();                                // reads done before next stage
  }

  if (mode == 1) {
    // ---- fused Q epilogue: RMS+RoPE, direct global stores (no LDS)
    int tg0 = (bm * 256 + wm * 128) & 4095;
    int bb  = (bm * 256) >> 12;
    int hh  = bn * 2 + wn;                           // head 0..15
    float w0 = qw[lo], w1 = qw[16 + lo], w2 = qw[32 + lo], w3 = qw[48 + lo];
    short* dst = qb2 + (size_t)((bb * 16 + hh) * 4096) * 64;
    const float2* tb = (const float2*)trig;
#pragma unroll
    for (int m = 0; m < 8; ++m)
#pragma unroll
      for (int r = 0; r < 4; ++r) {
        float x0 = acc[m][0][r], x1 = acc[m][1][r];
        float x2 = acc[m][2][r], x3 = acc[m][3][r];
        float ss = x0 * x0 + x1 * x1 + x2 * x2 + x3 * x3;
        ss += __shfl_xor(ss, 1); ss += __shfl_xor(ss, 2);
        ss += __shfl_xor(ss, 4); ss += __shfl_xor(ss, 8);
        float rn = rsqrtf(ss * 0.015625f + 1e-6f);
        x0 *= rn * w0; x1 *= rn * w1; x2 *= rn * w2; x3 *= rn * w3;
        int tp = tg0 + m * 16 + hi * 4 + r;
        float2 cs0 = tb[tp * 32 + lo];
        float2 cs1 = tb[tp * 32 + 16 + lo];
        float o0 = x0 * cs0.x - x2 * cs0.y;
        float o1 = x1 * cs1.x - x3 * cs1.y;
        float o2 = x2 * cs0.x + x0 * cs0.y;
        float o3 = x3 * cs1.x + x1 * cs1.y;
        size_t tb_ = (size_t)tp * 64;
        dst[tb_ + lo]      = (short)f2bf(o0);
        dst[tb_ + 16 + lo] = (short)f2bf(o1);
        dst[tb_ + 32 + lo] = (short)f2bf(o2);
        dst[tb_ + 48 + lo] = (short)f2bf(o3);
      }
    return;
  }

  // ---- mode 0: plain C write. layout col = lane&15, row = (lane>>4)*4 + reg
  int row0 = bm * 256 + wm * 128 + hi * 4;
  int col0 = bn * 128 + wn * 64 + lo;
  if (outBf16) {
    short* C = (short*)Cout;
#pragma unroll
    for (int m = 0; m < 8; ++m)
#pragma unroll
      for (int nf = 0; nf < 4; ++nf)
#pragma unroll
        for (int r = 0; r < 4; ++r)
          C[(size_t)(row0 + m * 16 + r) * N + col0 + nf * 16] = (short)f2bf(acc[m][nf][r]);
  } else {
    float* C = (float*)Cout;
#pragma unroll
    for (int m = 0; m < 8; ++m)
#pragma unroll
      for (int nf = 0; nf < 4; ++nf)
#pragma unroll
        for (int r = 0; r < 4; ++r)
          C[(size_t)(row0 + m * 16 + r) * N + col0 + nf * 16] = acc[m][nf][r];
  }
}

// ---------------- kernel: blocked sliding-window attention (swapped QK^T) ----
__global__ __launch_bounds__(256, 4) void k_attn(const short* __restrict__ qb,
                                                 const short* __restrict__ kb,
                                                 const short* __restrict__ vtg,
                                                 short* __restrict__ y) {
  __shared__ __align__(16) char smem[33792];
  short* ks  = (short*)smem;            // [128 key][64 d], chunk-XOR swizzled
  short* vts = (short*)(smem + 16384);  // [64 d][128 key], chunk-XOR swizzled
  int bid = blockIdx.x;
  int swz = (bid & 7) * 256 + (bid >> 3);          // XCD swizzle
  int h = swz & 15, n = (swz >> 4) & 31, b = swz >> 9;
  int tid = threadIdx.x, wid = tid >> 6, lane = tid & 63;
  int lo = lane & 31, hi = lane >> 5;

  const short* qrow = qb + (size_t)((b * 16 + h) * 4096 + n * 128 + wid * 32 + lo) * 64;
  short8 aq[4];
#pragma unroll
  for (int s = 0; s < 4; ++s) aq[s] = *(const short8*)(qrow + s * 16 + hi * 8);

  f32x16 O0 = {}, O1 = {};                         // O^T: rows d / d+32, col q
  float mrun = -1e30f, lrun = 0.f;
  int qr = wid * 32 + lo;
  const float SC = 0.125f * 1.4426950408889634f;   // scale * log2(e)

  for (int hf = (n == 0) ? 1 : 0; hf < 2; ++hf) {  // n==0: half0 fully masked
    int tg = (n - 1 + hf) * 128;                   // first key token (within b)
#pragma unroll
    for (int p = 0; p < 4; ++p) {
      int idx = p * 256 + tid;
      int r = idx >> 3, dc = idx & 7;
      gload16(kb + (size_t)(b * 4096 + tg + r) * 64 + ((dc ^ (r & 7)) << 3),
              ks + idx * 8);
    }
#pragma unroll
    for (int p = 0; p < 4; ++p) {
      int idx = p * 256 + tid;
      int dd = idx >> 4, s = idx & 15;
      gload16(vtg + (size_t)(b * 64 + dd) * 4096 + tg + ((s ^ (dd & 7)) << 3),
              vts + idx * 8);
    }
    __syncthreads();

#pragma unroll
    for (int mt = 0; mt < 4; ++mt) {
      f32x16 S = {};
      int r = mt * 32 + lo;
#pragma unroll
      for (int kst = 0; kst < 4; ++kst) {
        short8 kf = *(const short8*)&ks[r * 64 + ((((kst << 1) | hi) ^ (r & 7)) << 3)];
        S = mfma32(kf, aq[kst], S);
      }
#pragma unroll
      for (int rr = 0; rr < 16; ++rr) {
        int kg = hf * 128 + mt * 32 + (rr & 3) + ((rr >> 2) << 3) + (hi << 2);
        S[rr] = (kg >= qr && kg <= qr + 128) ? S[rr] * SC : -30000.f;
      }
      float pmax = S[0];
#pragma unroll
      for (int rr = 1; rr < 16; ++rr) pmax = fmaxf(pmax, S[rr]);
      pmax = fmaxf(pmax, __shfl_xor(pmax, 32));
      if (!__all(pmax - mrun <= 8.f)) {
        float mn = fmaxf(mrun, pmax);
        float al = exp2f(mrun - mn);
        lrun *= al; mrun = mn;
#pragma unroll
        for (int rr = 0; rr < 16; ++rr) { O0[rr] *= al; O1[rr] *= al; }
      }
      float ls = 0.f;
#pragma unroll
      for (int rr = 0; rr < 16; ++rr) { S[rr] = exp2f(S[rr] - mrun); ls += S[rr]; }
      ls += __shfl_xor(ls, 32);
      lrun += ls;
#pragma unroll
      for (int h2 = 0; h2 < 2; ++h2) {
        int b0 = h2 * 8;
        unsigned pk0 = cvtpk(S[b0 + 0], S[b0 + 1]);
        unsigned pk1 = cvtpk(S[b0 + 2], S[b0 + 3]);
        unsigned pk2 = cvtpk(S[b0 + 4], S[b0 + 5]);
        unsigned pk3 = cvtpk(S[b0 + 6], S[b0 + 7]);
        asm("v_permlane32_swap_b32 %0, %1" : "+v"(pk0), "+v"(pk2));
        asm("v_permlane32_swap_b32 %0, %1" : "+v"(pk1), "+v"(pk3));
        uint4v uw; uw.x = pk0; uw.y = pk1; uw.z = pk2; uw.w = pk3;
        short8 pb = __builtin_bit_cast(short8, uw);
        int kc = mt * 4 + h2 * 2 + hi;
        short8 vb0 = *(const short8*)&vts[lo * 128 + ((kc ^ (lo & 7)) << 3)];
        short8 vb1 = *(const short8*)&vts[(32 + lo) * 128 + ((kc ^ (lo & 7)) << 3)];
        O0 = mfma32(vb0, pb, O0);
        O1 = mfma32(vb1, pb, O1);
      }
    }
    __syncthreads();
  }

  float inv = 1.f / lrun;
  float* ot = (float*)smem + wid * 2112;           // [64 d][33] per wave
#pragma unroll
  for (int r = 0; r < 16; ++r) {
    int d0 = (r & 3) + ((r >> 2) << 3) + (hi << 2);
    ot[d0 * 33 + lo]        = O0[r] * inv;
    ot[(d0 + 32) * 33 + lo] = O1[r] * inv;
  }
  __syncthreads();
  int tok = lane >> 3, dc = lane & 7;
#pragma unroll
  for (int g = 0; g < 4; ++g) {
    int q = g * 8 + tok;
    short8 o8;
#pragma unroll
    for (int jj = 0; jj < 8; ++jj)
      o8[jj] = (short)f2bf(ot[(dc * 8 + jj) * 33 + q]);
    *(short8*)&y[(size_t)(b * 4096 + n * 128 + wid * 32 + q) * 1024 + h * 64 + dc * 8] = o8;
  }
}

// ---------------- launch ----------------
extern "C" void kernel_launch(void* const* d_in, const int* in_sizes, int n_in,
                              void* d_out, int out_size, void* d_ws, size_t ws_size,
                              hipStream_t stream) {
  const float* x      = (const float*)d_in[0];
  const int*   pos    = (const int*)d_in[1];
  const float* w_attn = (const float*)d_in[2];
  const float* w_proj = (const float*)d_in[3];
  const float* qw     = (const float*)d_in[4];
  const float* kw     = (const float*)d_in[5];

  char* ws = (char*)d_ws;
  short* xb   = (short*)ws;                         // 33,554,432 B (aliased as y later)
  short* wabt = (short*)(ws + 33554432);            //  2,359,296 B (1152 x 1024)
  short* wpbt = (short*)(ws + 35913728);            //  2,097,152 B
  short* qb2  = (short*)(ws + 38010880);            // 33,554,432 B
  short* kb2  = (short*)(ws + 71565312);            //  2,097,152 B
  short* vtg  = (short*)(ws + 73662464);            //  2,097,152 B
  float* trig = (float*)(ws + 75759616);            //  1,048,576 B (cos,sin pairs)
  short* ybuf = xb;                                 // xb dead after merged GEMM

  hipLaunchKernelGGL(k_prep, dim3(16384 + 1152 + 1024 + 512), dim3(256), 0, stream,
                     x, xb, w_attn, wabt, w_proj, wpbt, pos, trig);
  // merged dispatch: 128 KV blocks (first, co-scheduled) + 512 Q blocks
  hipLaunchKernelGGL(k_gemmbig, dim3(640), dim3(256), 0, stream, xb, wabt,
                     (void*)nullptr, 16384, 1024, 1024, 1, trig, qw, qb2, 1,
                     wabt + (size_t)1024 * 1024, kw, kb2, vtg);
  hipLaunchKernelGGL(k_attn, dim3(2048), dim3(256), 0, stream, qb2, kb2, vtg, ybuf);
  hipLaunchKernelGGL(k_gemmbig, dim3(512), dim3(256), 0, stream, ybuf, wpbt, d_out,
                     16384, 1024, 1024, 0,
                     (const float*)nullptr, (const float*)nullptr,
                     (short*)nullptr, 0,
                     (const short*)nullptr, (const float*)nullptr,
                     (short*)nullptr, (short*)nullptr);
}